// Round 1
// baseline (358.729 us; speedup 1.0000x reference)
//
#include <hip/hip_runtime.h>

#define NSIG  65536
#define KAT   512
#define CDIM  64

__device__ __forceinline__ float bcastf(float v, int l) {
  return __int_as_float(__builtin_amdgcn_readlane(__float_as_int(v), l));
}

// G = D^T D  [512][512]; DT[k][c] = D[c][k]
__global__ void k_gram(const float* __restrict__ D, float* __restrict__ G,
                       float* __restrict__ DT) {
  int tid = blockIdx.x * 256 + threadIdx.x;      // 262144 total
  int i = tid >> 9, j = tid & 511;
  float acc = 0.f;
  #pragma unroll 8
  for (int c = 0; c < CDIM; ++c) acc = fmaf(D[c * KAT + i], D[c * KAT + j], acc);
  G[tid] = acc;
  if (tid < KAT * CDIM) {
    int k = tid >> 6, c = tid & 63;
    DT[tid] = D[c * KAT + k];
  }
}

// ST[n][b] = z_e[b][n%64][n/2048][(n/64)%32]   (signal-major staging)
__global__ void k_tr(const float* __restrict__ ze, float* __restrict__ st) {
  __shared__ float tile[64][33];
  int cz = blockIdx.x >> 5;
  int h  = blockIdx.x & 31;
  int t  = threadIdx.x;
  #pragma unroll
  for (int q = 0; q < 8; ++q) {
    int idx = q * 256 + t;
    int b = idx >> 5, w = idx & 31;
    tile[b][w] = ze[b * 65536 + cz * 1024 + h * 32 + w];
  }
  __syncthreads();
  #pragma unroll
  for (int q = 0; q < 8; ++q) {
    int idx = q * 256 + t;
    int w = idx >> 6, b = idx & 63;
    st[(h * 2048 + w * 64 + cz) * 64 + b] = tile[b][w];
  }
}

__global__ __launch_bounds__(256) void k_omp(
    const float* __restrict__ D, const float* __restrict__ G,
    const float* __restrict__ DT, const float* __restrict__ ST,
    float* __restrict__ out0, float* __restrict__ lossp,
    float* __restrict__ coeffs) {
  const int lane = threadIdx.x & 63;
  const int wid  = (blockIdx.x * 256 + threadIdx.x) >> 6;   // 0..8191
  const int sig0 = wid * 8;

  // load 8 signals: lane r holds component r of each
  float s[8];
  #pragma unroll
  for (int m = 0; m < 8; ++m) s[m] = ST[(sig0 + m) * 64 + lane];

  // init_corr: lane holds atoms k = 8*lane + j
  float ic[8][8];
  #pragma unroll
  for (int m = 0; m < 8; ++m)
    #pragma unroll
    for (int j = 0; j < 8; ++j) ic[m][j] = 0.f;

  const float* Dp = D + 8 * lane;
  #pragma unroll 4
  for (int r = 0; r < 64; ++r) {
    const float4 d0 = *reinterpret_cast<const float4*>(Dp + r * KAT);
    const float4 d1 = *reinterpret_cast<const float4*>(Dp + r * KAT + 4);
    #pragma unroll
    for (int m = 0; m < 8; ++m) {
      const float sc = bcastf(s[m], r);
      ic[m][0] = fmaf(d0.x, sc, ic[m][0]);
      ic[m][1] = fmaf(d0.y, sc, ic[m][1]);
      ic[m][2] = fmaf(d0.z, sc, ic[m][2]);
      ic[m][3] = fmaf(d0.w, sc, ic[m][3]);
      ic[m][4] = fmaf(d1.x, sc, ic[m][4]);
      ic[m][5] = fmaf(d1.y, sc, ic[m][5]);
      ic[m][6] = fmaf(d1.z, sc, ic[m][6]);
      ic[m][7] = fmaf(d1.w, sc, ic[m][7]);
    }
  }

  float lossacc = 0.f;

  #pragma unroll
  for (int m = 0; m < 8; ++m) {
    const int n = sig0 + m;
    float bt[8];
    #pragma unroll
    for (int j = 0; j < 8; ++j) bt[j] = 0.f;
    int omega = 0xFF;
    int I0 = 0, I1 = 0, I2 = 0, I3 = 0, I4 = 0;
    float b0 = 0, b1 = 0, b2 = 0, b3 = 0, b4 = 0;
    // L: lower-tri 5x5, identity-padded; L00 == 1 always
    float L10 = 0, L11 = 1, L20 = 0, L21 = 0, L22 = 1;
    float L30 = 0, L31 = 0, L32 = 0, L33 = 1;
    float L40 = 0, L41 = 0, L42 = 0, L43 = 0, L44 = 1;
    float x0 = 0, x1 = 0, x2 = 0, x3 = 0, x4 = 0;

    #pragma unroll 1
    for (int it = 0; it < 5; ++it) {
      // ---- argmax of |init_corr - beta| * omega, first-index ties ----
      float best = -1.f; int bidx = 0;
      #pragma unroll
      for (int j = 0; j < 8; ++j) {
        float cr = ic[m][j] - bt[j];
        float a = fabsf(cr);
        a = ((omega >> j) & 1) ? a : 0.f;
        if (a > best) { best = a; bidx = (lane << 3) | j; }
      }
      #pragma unroll
      for (int off = 32; off > 0; off >>= 1) {
        float ov = __shfl_xor(best, off);
        int   oi = __shfl_xor(bidx, off);
        if (ov > best || (ov == best && oi < bidx)) { best = ov; bidx = oi; }
      }
      const int khat = __builtin_amdgcn_readfirstlane(bidx);
      if (lane == (khat >> 3)) omega &= ~(1 << (khat & 7));

      // ---- progressive Cholesky update (row `it`) ----
      if (it > 0) {
        float g0 = G[I0 * KAT + khat];
        float g1 = G[I1 * KAT + khat];
        float g2 = G[I2 * KAT + khat];
        float g3 = G[I3 * KAT + khat];
        float w0 = g0;                                   // /L00 == 1
        float w1 = (g1 - L10 * w0) / L11;
        float w2 = (g2 - L20 * w0 - L21 * w1) / L22;
        float w3 = (g3 - L30 * w0 - L31 * w1 - L32 * w2) / L33;
        if (it < 4) w3 = 0.f;
        if (it < 3) w2 = 0.f;
        if (it < 2) w1 = 0.f;
        float wbr = sqrtf(1.f - w0 * w0 - w1 * w1 - w2 * w2 - w3 * w3);
        if (it == 1) { L10 = w0; L11 = wbr; }
        if (it == 2) { L20 = w0; L21 = w1; L22 = wbr; }
        if (it == 3) { L30 = w0; L31 = w1; L32 = w2; L33 = wbr; }
        if (it == 4) { L40 = w0; L41 = w1; L42 = w2; L43 = w3; L44 = wbr; }
      }

      // ---- append index; gather b = init_corr[khat] ----
      {
        const int jj = khat & 7, sl = khat >> 3;
        float tmp = ic[m][0];
        if (jj == 1) tmp = ic[m][1];
        if (jj == 2) tmp = ic[m][2];
        if (jj == 3) tmp = ic[m][3];
        if (jj == 4) tmp = ic[m][4];
        if (jj == 5) tmp = ic[m][5];
        if (jj == 6) tmp = ic[m][6];
        if (jj == 7) tmp = ic[m][7];
        float bval = bcastf(tmp, sl);
        if (it == 0) { I0 = khat; b0 = bval; }
        if (it == 1) { I1 = khat; b1 = bval; }
        if (it == 2) { I2 = khat; b2 = bval; }
        if (it == 3) { I3 = khat; b3 = bval; }
        if (it == 4) { I4 = khat; b4 = bval; }
      }

      // ---- cholesky_solve: L y = b, L^T x = y (identity-padded 5x5) ----
      float y0 = b0;
      float y1 = (b1 - L10 * y0) / L11;
      float y2 = (b2 - L20 * y0 - L21 * y1) / L22;
      float y3 = (b3 - L30 * y0 - L31 * y1 - L32 * y2) / L33;
      float y4 = (b4 - L40 * y0 - L41 * y1 - L42 * y2 - L43 * y3) / L44;
      x4 = y4 / L44;
      x3 = (y3 - L43 * x4) / L33;
      x2 = (y2 - L32 * x3 - L42 * x4) / L22;
      x1 = (y1 - L21 * x2 - L31 * x3 - L41 * x4) / L11;
      x0 = (y0 - L10 * x1 - L20 * x2 - L30 * x3 - L40 * x4);

      // ---- beta = xs . G[I,:]  (skip on last iter) ----
      if (it < 4) {
        float nb0=0,nb1=0,nb2=0,nb3=0,nb4=0,nb5=0,nb6=0,nb7=0;
        #pragma unroll
        for (int t = 0; t < 5; ++t) {
          if (t <= it) {
            int It = I0; float xt = x0;
            if (t == 1) { It = I1; xt = x1; }
            if (t == 2) { It = I2; xt = x2; }
            if (t == 3) { It = I3; xt = x3; }
            if (t == 4) { It = I4; xt = x4; }
            const float4 ga = *reinterpret_cast<const float4*>(G + It * KAT + 8 * lane);
            const float4 gb = *reinterpret_cast<const float4*>(G + It * KAT + 8 * lane + 4);
            nb0 = fmaf(xt, ga.x, nb0);
            nb1 = fmaf(xt, ga.y, nb1);
            nb2 = fmaf(xt, ga.z, nb2);
            nb3 = fmaf(xt, ga.w, nb3);
            nb4 = fmaf(xt, gb.x, nb4);
            nb5 = fmaf(xt, gb.y, nb5);
            nb6 = fmaf(xt, gb.z, nb6);
            nb7 = fmaf(xt, gb.w, nb7);
          }
        }
        bt[0]=nb0; bt[1]=nb1; bt[2]=nb2; bt[3]=nb3;
        bt[4]=nb4; bt[5]=nb5; bt[6]=nb6; bt[7]=nb7;
      }
    } // it

    // ---- epilogue for this signal ----
    if (lane < 5) {
      int It = I0; float xt = x0;
      if (lane == 1) { It = I1; xt = x1; }
      if (lane == 2) { It = I2; xt = x2; }
      if (lane == 3) { It = I3; xt = x3; }
      if (lane == 4) { It = I4; xt = x4; }
      coeffs[(long)It * NSIG + n] = xt;
    }
    float rec = x0 * DT[I0 * 64 + lane];
    rec = fmaf(x1, DT[I1 * 64 + lane], rec);
    rec = fmaf(x2, DT[I2 * 64 + lane], rec);
    rec = fmaf(x3, DT[I3 * 64 + lane], rec);
    rec = fmaf(x4, DT[I4 * 64 + lane], rec);
    const float zv = s[m];
    const float d = rec - zv;
    lossacc = fmaf(d, d, lossacc);
    const int offn = (n & 63) * 1024 + (n >> 11) * 32 + ((n >> 6) & 31);
    out0[lane * 65536 + offn] = zv + d;   // z + (z_dl - z), faithful
  } // m

  #pragma unroll
  for (int off = 32; off > 0; off >>= 1) lossacc += __shfl_xor(lossacc, off);
  if (lane == 0) atomicAdd(lossp, lossacc * (1.25f / 4194304.f));
}

extern "C" void kernel_launch(void* const* d_in, const int* in_sizes, int n_in,
                              void* d_out, int out_size, void* d_ws, size_t ws_size,
                              hipStream_t stream) {
  const float* ze = (const float*)d_in[0];
  const float* D  = (const float*)d_in[1];
  float* out0 = (float*)d_out;
  float* lossp = out0 + 4194304;
  float* coeffs = out0 + 4194305;

  float* wsf = (float*)d_ws;
  float* G  = wsf;              // 262144 floats
  float* DT = wsf + 262144;     // 32768 floats
  float* ST = wsf + 294912;     // 4194304 floats

  // zero loss + coeffs (out0 is fully overwritten)
  hipMemsetAsync((char*)d_out + 16777216ull, 0, 134217732ull, stream);

  hipLaunchKernelGGL(k_gram, dim3(1024), dim3(256), 0, stream, D, G, DT);
  hipLaunchKernelGGL(k_tr,   dim3(2048), dim3(256), 0, stream, ze, ST);
  hipLaunchKernelGGL(k_omp,  dim3(2048), dim3(256), 0, stream,
                     D, G, DT, ST, out0, lossp, coeffs);
}

// Round 2
// 293.558 us; speedup vs baseline: 1.2220x; 1.2220x over previous
//
#include <hip/hip_runtime.h>

#define NSIG  65536
#define KAT   512
#define CDIM  64

__device__ __forceinline__ float bcastf(float v, int l) {
  return __int_as_float(__builtin_amdgcn_readlane(__float_as_int(v), l));
}

// G = D^T D  [512][512]; DT[k][c] = D[c][k]
__global__ void k_gram(const float* __restrict__ D, float* __restrict__ G,
                       float* __restrict__ DT) {
  int tid = blockIdx.x * 256 + threadIdx.x;      // 262144 total
  int i = tid >> 9, j = tid & 511;
  float acc = 0.f;
  #pragma unroll 8
  for (int c = 0; c < CDIM; ++c) acc = fmaf(D[c * KAT + i], D[c * KAT + j], acc);
  G[tid] = acc;
  if (tid < KAT * CDIM) {
    int k = tid >> 6, c = tid & 63;
    DT[tid] = D[c * KAT + k];
  }
}

// ST[n][b] = z_e[b][n%64][n/2048][(n/64)%32]   (signal-major staging)
__global__ void k_tr(const float* __restrict__ ze, float* __restrict__ st) {
  __shared__ float tile[64][33];
  int cz = blockIdx.x >> 5;
  int h  = blockIdx.x & 31;
  int t  = threadIdx.x;
  #pragma unroll
  for (int q = 0; q < 8; ++q) {
    int idx = q * 256 + t;
    int b = idx >> 5, w = idx & 31;
    tile[b][w] = ze[b * 65536 + cz * 1024 + h * 32 + w];
  }
  __syncthreads();
  #pragma unroll
  for (int q = 0; q < 8; ++q) {
    int idx = q * 256 + t;
    int w = idx >> 6, b = idx & 63;
    st[(h * 2048 + w * 64 + cz) * 64 + b] = tile[b][w];
  }
}

__global__ __launch_bounds__(256) void k_omp(
    const float* __restrict__ D, const float* __restrict__ G,
    const float* __restrict__ DT, const float* __restrict__ ST,
    float* __restrict__ out0, float* __restrict__ lossp,
    float* __restrict__ coeffs) {
  const int lane = threadIdx.x & 63;
  const int wid  = (blockIdx.x * 256 + threadIdx.x) >> 6;   // 0..8191
  const int sig0 = wid * 8;

  // load 8 signals: lane r holds component r of each
  float s[8];
  #pragma unroll
  for (int m = 0; m < 8; ++m) s[m] = ST[(sig0 + m) * 64 + lane];

  // init_corr: lane holds atoms k = 8*lane + j
  float ic[8][8];
  #pragma unroll
  for (int m = 0; m < 8; ++m)
    #pragma unroll
    for (int j = 0; j < 8; ++j) ic[m][j] = 0.f;

  const float* Dp = D + 8 * lane;
  #pragma unroll 4
  for (int r = 0; r < 64; ++r) {
    const float4 d0 = *reinterpret_cast<const float4*>(Dp + r * KAT);
    const float4 d1 = *reinterpret_cast<const float4*>(Dp + r * KAT + 4);
    #pragma unroll
    for (int m = 0; m < 8; ++m) {
      const float sc = bcastf(s[m], r);
      ic[m][0] = fmaf(d0.x, sc, ic[m][0]);
      ic[m][1] = fmaf(d0.y, sc, ic[m][1]);
      ic[m][2] = fmaf(d0.z, sc, ic[m][2]);
      ic[m][3] = fmaf(d0.w, sc, ic[m][3]);
      ic[m][4] = fmaf(d1.x, sc, ic[m][4]);
      ic[m][5] = fmaf(d1.y, sc, ic[m][5]);
      ic[m][6] = fmaf(d1.z, sc, ic[m][6]);
      ic[m][7] = fmaf(d1.w, sc, ic[m][7]);
    }
  }

  float lossacc = 0.f;

  #pragma unroll
  for (int m = 0; m < 8; ++m) {
    const int n = sig0 + m;
    float bt[8];
    #pragma unroll
    for (int j = 0; j < 8; ++j) bt[j] = 0.f;
    int omega = 0xFF;
    int I0 = 0, I1 = 0, I2 = 0, I3 = 0, I4 = 0;
    float b0 = 0, b1 = 0, b2 = 0, b3 = 0, b4 = 0;
    // L: lower-tri 5x5, identity-padded. Diagonals stored ONLY as inverses
    // (d1..d4, d0==1 implicit) via v_rsq_f32 — the reference only divides by
    // them, never multiplies. Off-diagonals stored as-is.
    float L10 = 0, L20 = 0, L21 = 0;
    float L30 = 0, L31 = 0, L32 = 0;
    float L40 = 0, L41 = 0, L42 = 0, L43 = 0;
    float d1 = 1.f, d2 = 1.f, d3 = 1.f, d4 = 1.f;
    float x0 = 0, x1 = 0, x2 = 0, x3 = 0, x4 = 0;

    #pragma unroll 1
    for (int it = 0; it < 5; ++it) {
      // ---- argmax of |init_corr - beta| * omega, first-index ties ----
      // key = (|corr| bits << 32) | ~atom_idx : unsigned max == argmax with
      // first-index tie-breaking (larger ~idx == smaller idx).
      unsigned long long key = 0ull;
      #pragma unroll
      for (int j = 0; j < 8; ++j) {
        float cr = ic[m][j] - bt[j];
        unsigned int ab = __float_as_uint(cr) & 0x7FFFFFFFu;
        ab = ((omega >> j) & 1) ? ab : 0u;
        unsigned long long kj =
            ((unsigned long long)ab << 32) | (unsigned int)(~((lane << 3) | j));
        key = kj > key ? kj : key;
      }
      #pragma unroll
      for (int off = 32; off > 0; off >>= 1) {
        unsigned long long ok = __shfl_xor(key, off);
        key = ok > key ? ok : key;
      }
      const int khat =
          __builtin_amdgcn_readfirstlane((int)(~(unsigned int)key)) & 511;
      if (lane == (khat >> 3)) omega &= ~(1 << (khat & 7));

      // ---- progressive Cholesky update (row `it`), divide-free ----
      if (it > 0) {
        float g0 = G[I0 * KAT + khat];
        float g1 = G[I1 * KAT + khat];
        float g2 = G[I2 * KAT + khat];
        float g3 = G[I3 * KAT + khat];
        float w0 = g0;                                   // * inv(L00) == 1
        float w1 = (g1 - L10 * w0) * d1;
        float w2 = (g2 - L20 * w0 - L21 * w1) * d2;
        float w3 = (g3 - L30 * w0 - L31 * w1 - L32 * w2) * d3;
        if (it < 4) w3 = 0.f;
        if (it < 3) w2 = 0.f;
        if (it < 2) w1 = 0.f;
        float s2 = 1.f - w0 * w0 - w1 * w1 - w2 * w2 - w3 * w3;
        float dn = __builtin_amdgcn_rsqf(s2);            // 1/sqrt, one instr
        if (it == 1) { L10 = w0; d1 = dn; }
        if (it == 2) { L20 = w0; L21 = w1; d2 = dn; }
        if (it == 3) { L30 = w0; L31 = w1; L32 = w2; d3 = dn; }
        if (it == 4) { L40 = w0; L41 = w1; L42 = w2; L43 = w3; d4 = dn; }
      }

      // ---- append index; gather b = init_corr[khat] ----
      {
        const int jj = khat & 7, sl = khat >> 3;
        float tmp = ic[m][0];
        if (jj == 1) tmp = ic[m][1];
        if (jj == 2) tmp = ic[m][2];
        if (jj == 3) tmp = ic[m][3];
        if (jj == 4) tmp = ic[m][4];
        if (jj == 5) tmp = ic[m][5];
        if (jj == 6) tmp = ic[m][6];
        if (jj == 7) tmp = ic[m][7];
        float bval = bcastf(tmp, sl);
        if (it == 0) { I0 = khat; b0 = bval; }
        if (it == 1) { I1 = khat; b1 = bval; }
        if (it == 2) { I2 = khat; b2 = bval; }
        if (it == 3) { I3 = khat; b3 = bval; }
        if (it == 4) { I4 = khat; b4 = bval; }
      }

      // ---- cholesky_solve: L y = b, L^T x = y — all multiplies ----
      float y0 = b0;
      float y1 = (b1 - L10 * y0) * d1;
      float y2 = (b2 - L20 * y0 - L21 * y1) * d2;
      float y3 = (b3 - L30 * y0 - L31 * y1 - L32 * y2) * d3;
      float y4 = (b4 - L40 * y0 - L41 * y1 - L42 * y2 - L43 * y3) * d4;
      x4 = y4 * d4;
      x3 = (y3 - L43 * x4) * d3;
      x2 = (y2 - L32 * x3 - L42 * x4) * d2;
      x1 = (y1 - L21 * x2 - L31 * x3 - L41 * x4) * d1;
      x0 = (y0 - L10 * x1 - L20 * x2 - L30 * x3 - L40 * x4);

      // ---- beta = xs . G[I,:]  (skip on last iter) ----
      if (it < 4) {
        float nb0=0,nb1=0,nb2=0,nb3=0,nb4=0,nb5=0,nb6=0,nb7=0;
        #pragma unroll
        for (int t = 0; t < 5; ++t) {
          if (t <= it) {
            int It = I0; float xt = x0;
            if (t == 1) { It = I1; xt = x1; }
            if (t == 2) { It = I2; xt = x2; }
            if (t == 3) { It = I3; xt = x3; }
            if (t == 4) { It = I4; xt = x4; }
            const float4 ga = *reinterpret_cast<const float4*>(G + It * KAT + 8 * lane);
            const float4 gb = *reinterpret_cast<const float4*>(G + It * KAT + 8 * lane + 4);
            nb0 = fmaf(xt, ga.x, nb0);
            nb1 = fmaf(xt, ga.y, nb1);
            nb2 = fmaf(xt, ga.z, nb2);
            nb3 = fmaf(xt, ga.w, nb3);
            nb4 = fmaf(xt, gb.x, nb4);
            nb5 = fmaf(xt, gb.y, nb5);
            nb6 = fmaf(xt, gb.z, nb6);
            nb7 = fmaf(xt, gb.w, nb7);
          }
        }
        bt[0]=nb0; bt[1]=nb1; bt[2]=nb2; bt[3]=nb3;
        bt[4]=nb4; bt[5]=nb5; bt[6]=nb6; bt[7]=nb7;
      }
    } // it

    // ---- epilogue for this signal ----
    if (lane < 5) {
      int It = I0; float xt = x0;
      if (lane == 1) { It = I1; xt = x1; }
      if (lane == 2) { It = I2; xt = x2; }
      if (lane == 3) { It = I3; xt = x3; }
      if (lane == 4) { It = I4; xt = x4; }
      coeffs[(long)It * NSIG + n] = xt;
    }
    float rec = x0 * DT[I0 * 64 + lane];
    rec = fmaf(x1, DT[I1 * 64 + lane], rec);
    rec = fmaf(x2, DT[I2 * 64 + lane], rec);
    rec = fmaf(x3, DT[I3 * 64 + lane], rec);
    rec = fmaf(x4, DT[I4 * 64 + lane], rec);
    const float zv = s[m];
    const float d = rec - zv;
    lossacc = fmaf(d, d, lossacc);
    const int offn = (n & 63) * 1024 + (n >> 11) * 32 + ((n >> 6) & 31);
    out0[lane * 65536 + offn] = zv + d;   // z + (z_dl - z), faithful
  } // m

  #pragma unroll
  for (int off = 32; off > 0; off >>= 1) lossacc += __shfl_xor(lossacc, off);
  if (lane == 0) atomicAdd(lossp, lossacc * (1.25f / 4194304.f));
}

extern "C" void kernel_launch(void* const* d_in, const int* in_sizes, int n_in,
                              void* d_out, int out_size, void* d_ws, size_t ws_size,
                              hipStream_t stream) {
  const float* ze = (const float*)d_in[0];
  const float* D  = (const float*)d_in[1];
  float* out0 = (float*)d_out;
  float* lossp = out0 + 4194304;
  float* coeffs = out0 + 4194305;

  float* wsf = (float*)d_ws;
  float* G  = wsf;              // 262144 floats
  float* DT = wsf + 262144;     // 32768 floats
  float* ST = wsf + 294912;     // 4194304 floats

  // zero loss + coeffs (out0 is fully overwritten)
  hipMemsetAsync((char*)d_out + 16777216ull, 0, 134217732ull, stream);

  hipLaunchKernelGGL(k_gram, dim3(1024), dim3(256), 0, stream, D, G, DT);
  hipLaunchKernelGGL(k_tr,   dim3(2048), dim3(256), 0, stream, ze, ST);
  hipLaunchKernelGGL(k_omp,  dim3(2048), dim3(256), 0, stream,
                     D, G, DT, ST, out0, lossp, coeffs);
}

// Round 3
// 255.446 us; speedup vs baseline: 1.4043x; 1.1492x over previous
//
#include <hip/hip_runtime.h>

#define NSIG  65536
#define KAT   512
#define CDIM  64

__device__ __forceinline__ float bcastf(float v, int l) {
  return __int_as_float(__builtin_amdgcn_readlane(__float_as_int(v), l));
}
__device__ __forceinline__ unsigned umaxu(unsigned a, unsigned b) {
  return a > b ? a : b;
}
__device__ __forceinline__ unsigned dppmax(unsigned v, const int ctrl) {
  // compile-time ctrl; row_mask/bank_mask full, bound_ctrl on
  switch (ctrl) {
    case 0xB1:  return umaxu(v, (unsigned)__builtin_amdgcn_mov_dpp((int)v, 0xB1, 0xF, 0xF, true));
    case 0x4E:  return umaxu(v, (unsigned)__builtin_amdgcn_mov_dpp((int)v, 0x4E, 0xF, 0xF, true));
    case 0x124: return umaxu(v, (unsigned)__builtin_amdgcn_mov_dpp((int)v, 0x124, 0xF, 0xF, true));
    default:    return umaxu(v, (unsigned)__builtin_amdgcn_mov_dpp((int)v, 0x128, 0xF, 0xF, true));
  }
}

// G = D^T D  [512][512]; DT[k][c] = D[c][k]
__global__ void k_gram(const float* __restrict__ D, float* __restrict__ G,
                       float* __restrict__ DT) {
  int tid = blockIdx.x * 256 + threadIdx.x;      // 262144 total
  int i = tid >> 9, j = tid & 511;
  float acc = 0.f;
  #pragma unroll 8
  for (int c = 0; c < CDIM; ++c) acc = fmaf(D[c * KAT + i], D[c * KAT + j], acc);
  G[tid] = acc;
  if (tid < KAT * CDIM) {
    int k = tid >> 6, c = tid & 63;
    DT[tid] = D[c * KAT + k];
  }
}

// ST[n][b] = z_e[b][n%64][n/2048][(n/64)%32]   (signal-major staging)
__global__ void k_tr(const float* __restrict__ ze, float* __restrict__ st) {
  __shared__ float tile[64][33];
  int cz = blockIdx.x >> 5;
  int h  = blockIdx.x & 31;
  int t  = threadIdx.x;
  #pragma unroll
  for (int q = 0; q < 8; ++q) {
    int idx = q * 256 + t;
    int b = idx >> 5, w = idx & 31;
    tile[b][w] = ze[b * 65536 + cz * 1024 + h * 32 + w];
  }
  __syncthreads();
  #pragma unroll
  for (int q = 0; q < 8; ++q) {
    int idx = q * 256 + t;
    int w = idx >> 6, b = idx & 63;
    st[(h * 2048 + w * 64 + cz) * 64 + b] = tile[b][w];
  }
}

__global__ __launch_bounds__(256) void k_omp(
    const float* __restrict__ D, const float* __restrict__ G,
    const float* __restrict__ DT, const float* __restrict__ ST,
    float* __restrict__ out0, float* __restrict__ lossp,
    float* __restrict__ coeffs) {
  const int lane = threadIdx.x & 63;
  const int wid  = (blockIdx.x * 256 + threadIdx.x) >> 6;   // 0..8191
  const int sig0 = wid * 8;

  // load 8 signals: lane r holds component r of each
  float s[8];
  #pragma unroll
  for (int m = 0; m < 8; ++m) s[m] = ST[(sig0 + m) * 64 + lane];

  // init_corr: lane holds atoms k = 8*lane + j
  float ic[8][8];
  #pragma unroll
  for (int m = 0; m < 8; ++m)
    #pragma unroll
    for (int j = 0; j < 8; ++j) ic[m][j] = 0.f;

  const float* Dp = D + 8 * lane;
  #pragma unroll 4
  for (int r = 0; r < 64; ++r) {
    const float4 d0 = *reinterpret_cast<const float4*>(Dp + r * KAT);
    const float4 d1 = *reinterpret_cast<const float4*>(Dp + r * KAT + 4);
    #pragma unroll
    for (int m = 0; m < 8; ++m) {
      const float sc = bcastf(s[m], r);
      ic[m][0] = fmaf(d0.x, sc, ic[m][0]);
      ic[m][1] = fmaf(d0.y, sc, ic[m][1]);
      ic[m][2] = fmaf(d0.z, sc, ic[m][2]);
      ic[m][3] = fmaf(d0.w, sc, ic[m][3]);
      ic[m][4] = fmaf(d1.x, sc, ic[m][4]);
      ic[m][5] = fmaf(d1.y, sc, ic[m][5]);
      ic[m][6] = fmaf(d1.z, sc, ic[m][6]);
      ic[m][7] = fmaf(d1.w, sc, ic[m][7]);
    }
  }

  float lossacc = 0.f;

  #pragma unroll
  for (int m = 0; m < 8; ++m) {
    const int n = sig0 + m;
    float bt[8];
    #pragma unroll
    for (int j = 0; j < 8; ++j) bt[j] = 0.f;
    int omega = 0xFF;
    int I0 = 0, I1 = 0, I2 = 0, I3 = 0, I4 = 0;
    float b0 = 0, b1 = 0, b2 = 0, b3 = 0, b4 = 0;
    // L: lower-tri 5x5, identity-padded; diagonals stored only as inverses.
    float L10 = 0, L20 = 0, L21 = 0;
    float L30 = 0, L31 = 0, L32 = 0;
    float L40 = 0, L41 = 0, L42 = 0, L43 = 0;
    float d1 = 1.f, d2 = 1.f, d3 = 1.f, d4 = 1.f;
    float x0 = 0, x1 = 0, x2 = 0, x3 = 0, x4 = 0;
    // cached G rows of the selected atoms (lane holds cols 8*lane..8*lane+7)
    float4 r0a, r0b, r1a, r1b, r2a, r2b, r3a, r3b;

    #pragma unroll 1
    for (int it = 0; it < 5; ++it) {
      // ---- argmax of |init_corr - beta| * omega: DPP, no LDS stages ----
      unsigned ab[8];
      #pragma unroll
      for (int j = 0; j < 8; ++j) {
        float cr = ic[m][j] - bt[j];
        unsigned a = __float_as_uint(cr) & 0x7FFFFFFFu;
        ab[j] = ((omega >> j) & 1) ? a : 0u;
      }
      unsigned la = umaxu(umaxu(umaxu(ab[0], ab[1]), umaxu(ab[2], ab[3])),
                          umaxu(umaxu(ab[4], ab[5]), umaxu(ab[6], ab[7])));
      unsigned rmax = la;
      rmax = dppmax(rmax, 0xB1);    // xor1 (quad_perm)
      rmax = dppmax(rmax, 0x4E);    // xor2 (quad_perm)
      rmax = dppmax(rmax, 0x124);   // row_ror:4
      rmax = dppmax(rmax, 0x128);   // row_ror:8  -> all 16 lanes of row have row max
      unsigned q0  = (unsigned)__builtin_amdgcn_readlane((int)rmax, 0);
      unsigned q16 = (unsigned)__builtin_amdgcn_readlane((int)rmax, 16);
      unsigned q32 = (unsigned)__builtin_amdgcn_readlane((int)rmax, 32);
      unsigned q48 = (unsigned)__builtin_amdgcn_readlane((int)rmax, 48);
      unsigned gmu = umaxu(umaxu(q0, q16), umaxu(q32, q48));
      unsigned long long ball = __ballot(la == gmu);
      const int sl = __ffsll((long long)ball) - 1;       // lowest winning lane
      int jb = 7;
      jb = (ab[6] == gmu) ? 6 : jb;
      jb = (ab[5] == gmu) ? 5 : jb;
      jb = (ab[4] == gmu) ? 4 : jb;
      jb = (ab[3] == gmu) ? 3 : jb;
      jb = (ab[2] == gmu) ? 2 : jb;
      jb = (ab[1] == gmu) ? 1 : jb;
      jb = (ab[0] == gmu) ? 0 : jb;
      const int khat = (sl << 3) | (__builtin_amdgcn_readlane(jb, sl) & 7);
      if (lane == sl) omega &= ~(1 << (khat & 7));

      // issue the new G row load immediately (consumed by beta after solve)
      float4 na, nbv;
      if (it < 4) {
        na  = *reinterpret_cast<const float4*>(G + khat * KAT + 8 * lane);
        nbv = *reinterpret_cast<const float4*>(G + khat * KAT + 8 * lane + 4);
      }

      const int jj = khat & 7;

      // ---- progressive Cholesky update (row `it`) from cached rows ----
      if (it > 0) {
        float g0 = 0.f, g1 = 0.f, g2 = 0.f, g3 = 0.f;
        {
          float e = r0a.x;
          e = (jj == 1) ? r0a.y : e; e = (jj == 2) ? r0a.z : e;
          e = (jj == 3) ? r0a.w : e; e = (jj == 4) ? r0b.x : e;
          e = (jj == 5) ? r0b.y : e; e = (jj == 6) ? r0b.z : e;
          e = (jj == 7) ? r0b.w : e;
          g0 = bcastf(e, sl);
        }
        if (it > 1) {
          float e = r1a.x;
          e = (jj == 1) ? r1a.y : e; e = (jj == 2) ? r1a.z : e;
          e = (jj == 3) ? r1a.w : e; e = (jj == 4) ? r1b.x : e;
          e = (jj == 5) ? r1b.y : e; e = (jj == 6) ? r1b.z : e;
          e = (jj == 7) ? r1b.w : e;
          g1 = bcastf(e, sl);
        }
        if (it > 2) {
          float e = r2a.x;
          e = (jj == 1) ? r2a.y : e; e = (jj == 2) ? r2a.z : e;
          e = (jj == 3) ? r2a.w : e; e = (jj == 4) ? r2b.x : e;
          e = (jj == 5) ? r2b.y : e; e = (jj == 6) ? r2b.z : e;
          e = (jj == 7) ? r2b.w : e;
          g2 = bcastf(e, sl);
        }
        if (it > 3) {
          float e = r3a.x;
          e = (jj == 1) ? r3a.y : e; e = (jj == 2) ? r3a.z : e;
          e = (jj == 3) ? r3a.w : e; e = (jj == 4) ? r3b.x : e;
          e = (jj == 5) ? r3b.y : e; e = (jj == 6) ? r3b.z : e;
          e = (jj == 7) ? r3b.w : e;
          g3 = bcastf(e, sl);
        }
        float w0 = g0;                                   // * inv(L00) == 1
        float w1 = (g1 - L10 * w0) * d1;
        float w2 = (g2 - L20 * w0 - L21 * w1) * d2;
        float w3 = (g3 - L30 * w0 - L31 * w1 - L32 * w2) * d3;
        if (it < 4) w3 = 0.f;
        if (it < 3) w2 = 0.f;
        if (it < 2) w1 = 0.f;
        float s2 = 1.f - w0 * w0 - w1 * w1 - w2 * w2 - w3 * w3;
        float dn = __builtin_amdgcn_rsqf(s2);            // 1/sqrt, one instr
        if (it == 1) { L10 = w0; d1 = dn; }
        if (it == 2) { L20 = w0; L21 = w1; d2 = dn; }
        if (it == 3) { L30 = w0; L31 = w1; L32 = w2; d3 = dn; }
        if (it == 4) { L40 = w0; L41 = w1; L42 = w2; L43 = w3; d4 = dn; }
      }

      // ---- append index; gather b = init_corr[khat] ----
      {
        float tmp = ic[m][0];
        if (jj == 1) tmp = ic[m][1];
        if (jj == 2) tmp = ic[m][2];
        if (jj == 3) tmp = ic[m][3];
        if (jj == 4) tmp = ic[m][4];
        if (jj == 5) tmp = ic[m][5];
        if (jj == 6) tmp = ic[m][6];
        if (jj == 7) tmp = ic[m][7];
        float bval = bcastf(tmp, sl);
        if (it == 0) { I0 = khat; b0 = bval; }
        if (it == 1) { I1 = khat; b1 = bval; }
        if (it == 2) { I2 = khat; b2 = bval; }
        if (it == 3) { I3 = khat; b3 = bval; }
        if (it == 4) { I4 = khat; b4 = bval; }
      }

      // ---- cholesky_solve: L y = b, L^T x = y — all multiplies ----
      float y0 = b0;
      float y1 = (b1 - L10 * y0) * d1;
      float y2 = (b2 - L20 * y0 - L21 * y1) * d2;
      float y3 = (b3 - L30 * y0 - L31 * y1 - L32 * y2) * d3;
      float y4 = (b4 - L40 * y0 - L41 * y1 - L42 * y2 - L43 * y3) * d4;
      x4 = y4 * d4;
      x3 = (y3 - L43 * x4) * d3;
      x2 = (y2 - L32 * x3 - L42 * x4) * d2;
      x1 = (y1 - L21 * x2 - L31 * x3 - L41 * x4) * d1;
      x0 = (y0 - L10 * x1 - L20 * x2 - L30 * x3 - L40 * x4);

      // ---- cache new row; beta = xs . G[I,:] from cached rows ----
      if (it < 4) {
        if (it == 0) { r0a = na; r0b = nbv; }
        if (it == 1) { r1a = na; r1b = nbv; }
        if (it == 2) { r2a = na; r2b = nbv; }
        if (it == 3) { r3a = na; r3b = nbv; }
        float nb0 = x0 * r0a.x, nb1 = x0 * r0a.y, nb2 = x0 * r0a.z, nb3 = x0 * r0a.w;
        float nb4 = x0 * r0b.x, nb5 = x0 * r0b.y, nb6 = x0 * r0b.z, nb7 = x0 * r0b.w;
        if (it >= 1) {
          nb0 = fmaf(x1, r1a.x, nb0); nb1 = fmaf(x1, r1a.y, nb1);
          nb2 = fmaf(x1, r1a.z, nb2); nb3 = fmaf(x1, r1a.w, nb3);
          nb4 = fmaf(x1, r1b.x, nb4); nb5 = fmaf(x1, r1b.y, nb5);
          nb6 = fmaf(x1, r1b.z, nb6); nb7 = fmaf(x1, r1b.w, nb7);
        }
        if (it >= 2) {
          nb0 = fmaf(x2, r2a.x, nb0); nb1 = fmaf(x2, r2a.y, nb1);
          nb2 = fmaf(x2, r2a.z, nb2); nb3 = fmaf(x2, r2a.w, nb3);
          nb4 = fmaf(x2, r2b.x, nb4); nb5 = fmaf(x2, r2b.y, nb5);
          nb6 = fmaf(x2, r2b.z, nb6); nb7 = fmaf(x2, r2b.w, nb7);
        }
        if (it >= 3) {
          nb0 = fmaf(x3, r3a.x, nb0); nb1 = fmaf(x3, r3a.y, nb1);
          nb2 = fmaf(x3, r3a.z, nb2); nb3 = fmaf(x3, r3a.w, nb3);
          nb4 = fmaf(x3, r3b.x, nb4); nb5 = fmaf(x3, r3b.y, nb5);
          nb6 = fmaf(x3, r3b.z, nb6); nb7 = fmaf(x3, r3b.w, nb7);
        }
        bt[0] = nb0; bt[1] = nb1; bt[2] = nb2; bt[3] = nb3;
        bt[4] = nb4; bt[5] = nb5; bt[6] = nb6; bt[7] = nb7;
      }
    } // it

    // ---- epilogue for this signal ----
    if (lane < 5) {
      int It = I0; float xt = x0;
      if (lane == 1) { It = I1; xt = x1; }
      if (lane == 2) { It = I2; xt = x2; }
      if (lane == 3) { It = I3; xt = x3; }
      if (lane == 4) { It = I4; xt = x4; }
      coeffs[(long)It * NSIG + n] = xt;
    }
    float rec = x0 * DT[I0 * 64 + lane];
    rec = fmaf(x1, DT[I1 * 64 + lane], rec);
    rec = fmaf(x2, DT[I2 * 64 + lane], rec);
    rec = fmaf(x3, DT[I3 * 64 + lane], rec);
    rec = fmaf(x4, DT[I4 * 64 + lane], rec);
    const float zv = s[m];
    const float d = rec - zv;
    lossacc = fmaf(d, d, lossacc);
    const int offn = (n & 63) * 1024 + (n >> 11) * 32 + ((n >> 6) & 31);
    out0[lane * 65536 + offn] = zv + d;   // z + (z_dl - z), faithful
  } // m

  #pragma unroll
  for (int off = 32; off > 0; off >>= 1) lossacc += __shfl_xor(lossacc, off);
  if (lane == 0) atomicAdd(lossp, lossacc * (1.25f / 4194304.f));
}

extern "C" void kernel_launch(void* const* d_in, const int* in_sizes, int n_in,
                              void* d_out, int out_size, void* d_ws, size_t ws_size,
                              hipStream_t stream) {
  const float* ze = (const float*)d_in[0];
  const float* D  = (const float*)d_in[1];
  float* out0 = (float*)d_out;
  float* lossp = out0 + 4194304;
  float* coeffs = out0 + 4194305;

  float* wsf = (float*)d_ws;
  float* G  = wsf;              // 262144 floats
  float* DT = wsf + 262144;     // 32768 floats
  float* ST = wsf + 294912;     // 4194304 floats

  // zero loss + coeffs (out0 is fully overwritten)
  hipMemsetAsync((char*)d_out + 16777216ull, 0, 134217732ull, stream);

  hipLaunchKernelGGL(k_gram, dim3(1024), dim3(256), 0, stream, D, G, DT);
  hipLaunchKernelGGL(k_tr,   dim3(2048), dim3(256), 0, stream, ze, ST);
  hipLaunchKernelGGL(k_omp,  dim3(2048), dim3(256), 0, stream,
                     D, G, DT, ST, out0, lossp, coeffs);
}